// Round 1
// baseline (983.321 us; speedup 1.0000x reference)
//
#include <hip/hip_runtime.h>
#include <math.h>

#define ALPHA_F 0.4f
#define FP32_EPS 1.1920928955078125e-7f
#define NB 256        // batch
#define NV 128000     // vocab
#define NR 64         // rank

// Workspace layout (d_ws): [0..8): 2x uint32 abs-max slots (maxL, maxLp)
//                          [256..256+65536): P[256][64] fp32

// ---------------- Kernel 1a: split-K partials of P = L @ W ----------------
// grid (500 chunks, 2 rowgroups), block 256 (4 waves). Each wave: 32 rows,
// lane = rank. K-chunk = 256. Partials -> Ppart[chunk][256][64] (in d_out scratch).
__global__ __launch_bounds__(256) void k1_partial(const float* __restrict__ L,
                                                  const float* __restrict__ W,
                                                  float* __restrict__ Ppart) {
    const int lane = threadIdx.x & 63;
    const int w    = __builtin_amdgcn_readfirstlane(threadIdx.x >> 6);
    const int chunk = blockIdx.x;            // 0..499
    const int k0    = chunk * 256;
    const int row0  = blockIdx.y * 128 + w * 32;

    float acc[32];
#pragma unroll
    for (int i = 0; i < 32; ++i) acc[i] = 0.f;

    const float* Wk = W + (size_t)k0 * NR + lane;

    for (int kk = 0; kk < 64; ++kk) {
        const int k = k0 + kk * 4;
        const float w0 = Wk[(size_t)(kk * 4 + 0) * NR];
        const float w1 = Wk[(size_t)(kk * 4 + 1) * NR];
        const float w2 = Wk[(size_t)(kk * 4 + 2) * NR];
        const float w3 = Wk[(size_t)(kk * 4 + 3) * NR];
#pragma unroll
        for (int i = 0; i < 32; ++i) {
            // wave-uniform address -> scalar load (s_load_dwordx4)
            const float4 lv = *(const float4*)(L + (size_t)(row0 + i) * NV + k);
            acc[i] = fmaf(lv.x, w0, acc[i]);
            acc[i] = fmaf(lv.y, w1, acc[i]);
            acc[i] = fmaf(lv.z, w2, acc[i]);
            acc[i] = fmaf(lv.w, w3, acc[i]);
        }
    }

    float* outp = Ppart + (size_t)chunk * (NB * NR);
#pragma unroll
    for (int i = 0; i < 32; ++i) outp[(row0 + i) * NR + lane] = acc[i];
}

// ---------------- Kernel 1b: reduce partials -> P, zero max slots ----------------
// grid 256, block 256. Wave w sums chunks [w*125,(w+1)*125) for 64 columns.
__global__ __launch_bounds__(256) void k1_reduce(const float* __restrict__ Ppart,
                                                 float* __restrict__ P,
                                                 unsigned* __restrict__ maxbits) {
    __shared__ float partial[4][64];
    const int lane = threadIdx.x & 63;
    const int w    = threadIdx.x >> 6;
    const int col  = blockIdx.x * 64 + lane;   // 0..16383

    float s = 0.f;
    for (int c = w * 125; c < (w + 1) * 125; ++c)
        s += Ppart[(size_t)c * (NB * NR) + col];
    partial[w][lane] = s;
    __syncthreads();
    if (w == 0) {
        P[col] = partial[0][lane] + partial[1][lane] + partial[2][lane] + partial[3][lane];
        if (blockIdx.x == 0 && lane < 2) maxbits[lane] = 0u;
    }
}

// ---------------- Kernels 2/3 shared shape ----------------
// grid (2000 v-tiles, 4 b-quarters), block 256. Thread: v = tile*64+lane,
// W[v][:] in 64 VGPRs; P quarter (64 rows) staged in LDS, broadcast reads.
// Wave w handles 16 b rows.

__global__ __launch_bounds__(256) void k2_maxes(const float* __restrict__ L,
                                                const float* __restrict__ W,
                                                const float* __restrict__ P,
                                                unsigned* __restrict__ maxbits) {
    __shared__ float Pl[64 * NR];     // 16 KB
    __shared__ unsigned red[8];
    const int lane = threadIdx.x & 63;
    const int w    = __builtin_amdgcn_readfirstlane(threadIdx.x >> 6);
    const int v    = blockIdx.x * 64 + lane;
    const int bq   = blockIdx.y;

    {
        const float4* src = (const float4*)(P + (size_t)bq * 64 * NR);
        float4* dst = (float4*)Pl;
        for (int i = threadIdx.x; i < (64 * NR) / 4; i += 256) dst[i] = src[i];
    }
    float wreg[64];
    {
        const float4* Wv = (const float4*)(W + (size_t)v * NR);
#pragma unroll
        for (int rr = 0; rr < 16; ++rr) {
            const float4 t = Wv[rr];
            wreg[4 * rr + 0] = t.x; wreg[4 * rr + 1] = t.y;
            wreg[4 * rr + 2] = t.z; wreg[4 * rr + 3] = t.w;
        }
    }
    __syncthreads();

    float mL = 0.f, mLp = 0.f;
    for (int i = 0; i < 16; ++i) {
        const int bl = w * 16 + i;
        const float l = L[(size_t)(bq * 64 + bl) * NV + v];
        float acc = -l;
        const float4* prow = (const float4*)(Pl + bl * NR);
#pragma unroll
        for (int rr = 0; rr < 16; ++rr) {
            const float4 p = prow[rr];   // broadcast ds_read_b128
            acc = fmaf(p.x, wreg[4 * rr + 0], acc);
            acc = fmaf(p.y, wreg[4 * rr + 1], acc);
            acc = fmaf(p.z, wreg[4 * rr + 2], acc);
            acc = fmaf(p.w, wreg[4 * rr + 3], acc);
        }
        mL  = fmaxf(mL,  fabsf(l));
        mLp = fmaxf(mLp, fabsf(acc));
    }
#pragma unroll
    for (int off = 32; off > 0; off >>= 1) {
        mL  = fmaxf(mL,  __shfl_xor(mL,  off, 64));
        mLp = fmaxf(mLp, __shfl_xor(mLp, off, 64));
    }
    if (lane == 0) { red[w * 2] = __float_as_uint(mL); red[w * 2 + 1] = __float_as_uint(mLp); }
    __syncthreads();
    if (threadIdx.x == 0) {
        unsigned a = red[0], b = red[1];
        for (int q = 1; q < 4; ++q) {
            a = a > red[q * 2]     ? a : red[q * 2];
            b = b > red[q * 2 + 1] ? b : red[q * 2 + 1];
        }
        atomicMax(&maxbits[0], a);   // abs-float bits: uint order == float order
        atomicMax(&maxbits[1], b);
    }
}

__global__ __launch_bounds__(256) void k3_out(const float* __restrict__ L,
                                              const float* __restrict__ W,
                                              const float* __restrict__ P,
                                              const unsigned* __restrict__ maxbits,
                                              float* __restrict__ out) {
    __shared__ float Pl[64 * NR];
    const int lane = threadIdx.x & 63;
    const int w    = __builtin_amdgcn_readfirstlane(threadIdx.x >> 6);
    const int v    = blockIdx.x * 64 + lane;
    const int bq   = blockIdx.y;

    const float maxL  = __uint_as_float(maxbits[0]);
    const float maxLp = __uint_as_float(maxbits[1]);
    const float scale = maxL / fmaxf(maxLp, FP32_EPS);
    const float c1 = (1.f - ALPHA_F) * scale;

    {
        const float4* src = (const float4*)(P + (size_t)bq * 64 * NR);
        float4* dst = (float4*)Pl;
        for (int i = threadIdx.x; i < (64 * NR) / 4; i += 256) dst[i] = src[i];
    }
    float wreg[64];
    {
        const float4* Wv = (const float4*)(W + (size_t)v * NR);
#pragma unroll
        for (int rr = 0; rr < 16; ++rr) {
            const float4 t = Wv[rr];
            wreg[4 * rr + 0] = t.x; wreg[4 * rr + 1] = t.y;
            wreg[4 * rr + 2] = t.z; wreg[4 * rr + 3] = t.w;
        }
    }
    __syncthreads();

    for (int i = 0; i < 16; ++i) {
        const int bl = w * 16 + i;
        const size_t off = (size_t)(bq * 64 + bl) * NV + v;
        const float l = L[off];
        float acc = -l;
        const float4* prow = (const float4*)(Pl + bl * NR);
#pragma unroll
        for (int rr = 0; rr < 16; ++rr) {
            const float4 p = prow[rr];
            acc = fmaf(p.x, wreg[4 * rr + 0], acc);
            acc = fmaf(p.y, wreg[4 * rr + 1], acc);
            acc = fmaf(p.z, wreg[4 * rr + 2], acc);
            acc = fmaf(p.w, wreg[4 * rr + 3], acc);
        }
        out[off] = fmaf(c1, acc, ALPHA_F * l);   // 0.6*scale*Lp + 0.4*L
    }
}

extern "C" void kernel_launch(void* const* d_in, const int* in_sizes, int n_in,
                              void* d_out, int out_size, void* d_ws, size_t ws_size,
                              hipStream_t stream) {
    const float* L = (const float*)d_in[1];   // logits [256,128000]
    const float* W = (const float*)d_in[2];   // W [128000,64]
    float* out = (float*)d_out;

    unsigned* maxbits = (unsigned*)d_ws;
    float* P = (float*)((char*)d_ws + 256);
    float* Ppart = out;   // d_out as scratch: 500*16384 floats << out_size

    k1_partial<<<dim3(500, 2), 256, 0, stream>>>(L, W, Ppart);
    k1_reduce <<<256,          256, 0, stream>>>(Ppart, P, maxbits);
    k2_maxes  <<<dim3(2000, 4), 256, 0, stream>>>(L, W, P, maxbits);
    k3_out    <<<dim3(2000, 4), 256, 0, stream>>>(L, W, P, maxbits, out);
}

// Round 2
// 409.975 us; speedup vs baseline: 2.3985x; 2.3985x over previous
//
#include <hip/hip_runtime.h>
#include <math.h>

#define ALPHA_F 0.4f
#define FP32_EPS 1.1920928955078125e-7f
#define NB 256
#define NV 128000
#define NR 64

typedef _Float16 half_t;
typedef _Float16 half2_t __attribute__((ext_vector_type(2)));
typedef _Float16 half8 __attribute__((ext_vector_type(8)));
typedef float f32x4 __attribute__((ext_vector_type(4)));

// ws layout:   [0..8)   2x uint32 maxbits (maxL, maxLp)
//              [256..256+65536) P[256][64] fp32
// d_out scratch (dead before k3 rewrites all of d_out):
//              [0..32MB)          Ppart[500][256][64] fp32
//              [32MiB..32MiB+16MB) WhT[64][128000] fp16

// ---------- k0: W fp32 -> WhT fp16 (transposed), zero P/maxbits ----------
__global__ __launch_bounds__(256) void k0_prep(const float* __restrict__ W,
                                               half_t* __restrict__ WhT,
                                               float* __restrict__ P,
                                               unsigned* __restrict__ maxbits) {
    __shared__ half_t tile[256 * 66];   // pad 64 -> 66 halves
    const int t  = threadIdx.x;
    const int k0 = blockIdx.x * 256;

    if (blockIdx.x < 64) P[blockIdx.x * 256 + t] = 0.f;
    if (blockIdx.x == 0 && t < 2) maxbits[t] = 0u;

    // phase 1: coalesced read of W[256k x 64n] tile, cvt, LDS store (half2 = 4B aligned)
#pragma unroll
    for (int i = 0; i < 16; ++i) {
        const int f  = i * 256 + t;       // 0..4095
        const int kr = f >> 4;            // row in tile
        const int n4 = (f & 15) * 4;      // col group
        const float4 v = *(const float4*)(W + (size_t)(k0 + kr) * NR + n4);
        half2_t h01 = { (half_t)v.x, (half_t)v.y };
        half2_t h23 = { (half_t)v.z, (half_t)v.w };
        *(half2_t*)&tile[kr * 66 + n4]     = h01;
        *(half2_t*)&tile[kr * 66 + n4 + 2] = h23;
    }
    __syncthreads();

    // phase 2: gather LDS column, store WhT rows with dwordx4
    const int n   = t >> 2;
    const int seg = t & 3;
#pragma unroll
    for (int i = 0; i < 8; ++i) {
        const int kk = (i * 4 + seg) * 8;
        half8 v;
#pragma unroll
        for (int j = 0; j < 8; ++j) v[j] = tile[(kk + j) * 66 + n];
        *(half8*)(WhT + (size_t)n * NV + k0 + kk) = v;
    }
}

// ---------- k1: split-K MFMA partials of P = L @ W, harvest max|L| ----------
// grid 500 (K-chunks of 256); block 256 = 4 waves; block covers M=256, N=64.
__global__ __launch_bounds__(256) void k1_pmm(const float* __restrict__ L,
                                              const half_t* __restrict__ WhT,
                                              float* __restrict__ Ppart,
                                              unsigned* __restrict__ maxbits) {
    const int l  = threadIdx.x & 63;
    const int w  = threadIdx.x >> 6;
    const int q  = l >> 4;
    const int il = l & 15;
    const int k0 = blockIdx.x * 256;

    f32x4 acc[4][4] = {};   // [mt][nt]
    float amax = 0.f;

    for (int ks = 0; ks < 8; ++ks) {
        const int kk = k0 + ks * 32 + q * 8;
        half8 b[4];
#pragma unroll
        for (int nt = 0; nt < 4; ++nt)
            b[nt] = *(const half8*)(WhT + (size_t)(nt * 16 + il) * NV + kk);
#pragma unroll
        for (int mt = 0; mt < 4; ++mt) {
            const float* lp = L + (size_t)(mt * 64 + w * 16 + il) * NV + kk;
            const float4 f0 = *(const float4*)lp;
            const float4 f1 = *(const float4*)(lp + 4);
            amax = fmaxf(amax, fmaxf(fmaxf(fabsf(f0.x), fabsf(f0.y)),
                                     fmaxf(fabsf(f0.z), fabsf(f0.w))));
            amax = fmaxf(amax, fmaxf(fmaxf(fabsf(f1.x), fabsf(f1.y)),
                                     fmaxf(fabsf(f1.z), fabsf(f1.w))));
            half8 a = { (half_t)f0.x, (half_t)f0.y, (half_t)f0.z, (half_t)f0.w,
                        (half_t)f1.x, (half_t)f1.y, (half_t)f1.z, (half_t)f1.w };
#pragma unroll
            for (int nt = 0; nt < 4; ++nt)
                acc[mt][nt] = __builtin_amdgcn_mfma_f32_16x16x32_f16(a, b[nt], acc[mt][nt], 0, 0, 0);
        }
    }

    float* pb = Ppart + (size_t)blockIdx.x * (NB * NR);
#pragma unroll
    for (int mt = 0; mt < 4; ++mt)
#pragma unroll
        for (int nt = 0; nt < 4; ++nt)
#pragma unroll
            for (int i = 0; i < 4; ++i)
                pb[(mt * 64 + w * 16 + q * 4 + i) * NR + nt * 16 + il] = acc[mt][nt][i];

    // max|L| reduction
#pragma unroll
    for (int off = 32; off > 0; off >>= 1)
        amax = fmaxf(amax, __shfl_xor(amax, off, 64));
    __shared__ float red[4];
    if (l == 0) red[w] = amax;
    __syncthreads();
    if (threadIdx.x == 0) {
        float m = fmaxf(fmaxf(red[0], red[1]), fmaxf(red[2], red[3]));
        atomicMax(&maxbits[0], __float_as_uint(m));
    }
}

// ---------- k1b: reduce partials into P fp32 ----------
// grid (64, 10); thread sums 50 slices, one atomicAdd.
__global__ __launch_bounds__(256) void k1b_reduce(const float* __restrict__ Ppart,
                                                  float* __restrict__ P) {
    const int g = blockIdx.x * 256 + threadIdx.x;   // 0..16383
    const float* p = Ppart + (size_t)blockIdx.y * 50 * (NB * NR) + g;
    float s = 0.f;
#pragma unroll 5
    for (int i = 0; i < 50; ++i) s += p[(size_t)i * (NB * NR)];
    atomicAdd(&P[g], s);
}

// ---------- k2: max|P@Wt - L| via MFMA ----------
// grid (125 n-chunks of 1024, 4 m-groups of 64); wave = one 16-row m-tile.
__global__ __launch_bounds__(256) void k2_max(const float* __restrict__ L,
                                              const float* __restrict__ W,
                                              const float* __restrict__ P,
                                              unsigned* __restrict__ maxbits) {
    const int l  = threadIdx.x & 63;
    const int w  = threadIdx.x >> 6;
    const int q  = l >> 4;
    const int il = l & 15;
    const int m0 = blockIdx.y * 64 + w * 16;

    half8 a[2];
#pragma unroll
    for (int ks = 0; ks < 2; ++ks) {
        const float* pp = P + (m0 + il) * NR + ks * 32 + q * 8;
        const float4 f0 = *(const float4*)pp;
        const float4 f1 = *(const float4*)(pp + 4);
        a[ks] = { (half_t)f0.x, (half_t)f0.y, (half_t)f0.z, (half_t)f0.w,
                  (half_t)f1.x, (half_t)f1.y, (half_t)f1.z, (half_t)f1.w };
    }

    float mx = 0.f;
    for (int it = 0; it < 64; ++it) {
        const int n0 = blockIdx.x * 1024 + it * 16;
        half8 b[2];
#pragma unroll
        for (int ks = 0; ks < 2; ++ks) {
            const float* wp = W + (size_t)(n0 + il) * NR + ks * 32 + q * 8;
            const float4 f0 = *(const float4*)wp;
            const float4 f1 = *(const float4*)(wp + 4);
            b[ks] = { (half_t)f0.x, (half_t)f0.y, (half_t)f0.z, (half_t)f0.w,
                      (half_t)f1.x, (half_t)f1.y, (half_t)f1.z, (half_t)f1.w };
        }
        f32x4 acc = {};
        acc = __builtin_amdgcn_mfma_f32_16x16x32_f16(a[0], b[0], acc, 0, 0, 0);
        acc = __builtin_amdgcn_mfma_f32_16x16x32_f16(a[1], b[1], acc, 0, 0, 0);
        const size_t rowb = (size_t)(m0 + q * 4) * NV + n0 + il;
#pragma unroll
        for (int i = 0; i < 4; ++i) {
            const float lv = L[rowb + (size_t)i * NV];
            mx = fmaxf(mx, fabsf(acc[i] - lv));
        }
    }

#pragma unroll
    for (int off = 32; off > 0; off >>= 1)
        mx = fmaxf(mx, __shfl_xor(mx, off, 64));
    __shared__ float red[4];
    if (l == 0) red[w] = mx;
    __syncthreads();
    if (threadIdx.x == 0) {
        float m = fmaxf(fmaxf(red[0], red[1]), fmaxf(red[2], red[3]));
        atomicMax(&maxbits[1], __float_as_uint(m));
    }
}

// ---------- k3: out = 0.6*scale*(P@Wt - L) + 0.4*L ----------
__global__ __launch_bounds__(256) void k3_out(const float* __restrict__ L,
                                              const float* __restrict__ W,
                                              const float* __restrict__ P,
                                              const unsigned* __restrict__ maxbits,
                                              float* __restrict__ out) {
    const int l  = threadIdx.x & 63;
    const int w  = threadIdx.x >> 6;
    const int q  = l >> 4;
    const int il = l & 15;
    const int m0 = blockIdx.y * 64 + w * 16;

    const float maxL  = __uint_as_float(maxbits[0]);
    const float maxLp = fmaxf(__uint_as_float(maxbits[1]), FP32_EPS);
    const float scale = maxL / maxLp;
    const float c1 = (1.f - ALPHA_F) * scale;    // on (acc - l)
    const float c0 = ALPHA_F;                    // on l

    half8 a[2];
#pragma unroll
    for (int ks = 0; ks < 2; ++ks) {
        const float* pp = P + (m0 + il) * NR + ks * 32 + q * 8;
        const float4 f0 = *(const float4*)pp;
        const float4 f1 = *(const float4*)(pp + 4);
        a[ks] = { (half_t)f0.x, (half_t)f0.y, (half_t)f0.z, (half_t)f0.w,
                  (half_t)f1.x, (half_t)f1.y, (half_t)f1.z, (half_t)f1.w };
    }

    for (int it = 0; it < 64; ++it) {
        const int n0 = blockIdx.x * 1024 + it * 16;
        half8 b[2];
#pragma unroll
        for (int ks = 0; ks < 2; ++ks) {
            const float* wp = W + (size_t)(n0 + il) * NR + ks * 32 + q * 8;
            const float4 f0 = *(const float4*)wp;
            const float4 f1 = *(const float4*)(wp + 4);
            b[ks] = { (half_t)f0.x, (half_t)f0.y, (half_t)f0.z, (half_t)f0.w,
                      (half_t)f1.x, (half_t)f1.y, (half_t)f1.z, (half_t)f1.w };
        }
        f32x4 acc = {};
        acc = __builtin_amdgcn_mfma_f32_16x16x32_f16(a[0], b[0], acc, 0, 0, 0);
        acc = __builtin_amdgcn_mfma_f32_16x16x32_f16(a[1], b[1], acc, 0, 0, 0);
        const size_t rowb = (size_t)(m0 + q * 4) * NV + n0 + il;
#pragma unroll
        for (int i = 0; i < 4; ++i) {
            const float lv = L[rowb + (size_t)i * NV];
            out[rowb + (size_t)i * NV] = fmaf(c1, acc[i] - lv, c0 * lv);
        }
    }
}

extern "C" void kernel_launch(void* const* d_in, const int* in_sizes, int n_in,
                              void* d_out, int out_size, void* d_ws, size_t ws_size,
                              hipStream_t stream) {
    const float* L = (const float*)d_in[1];   // logits [256,128000]
    const float* W = (const float*)d_in[2];   // W [128000,64]
    float* out = (float*)d_out;

    unsigned* maxbits = (unsigned*)d_ws;
    float*    P       = (float*)((char*)d_ws + 256);

    float*  Ppart = (float*)d_out;                              // 32 MB
    half_t* WhT   = (half_t*)((char*)d_out + (32u << 20));      // 16 MB @ 32MiB

    k0_prep  <<<500,          256, 0, stream>>>(W, WhT, P, maxbits);
    k1_pmm   <<<500,          256, 0, stream>>>(L, WhT, Ppart, maxbits);
    k1b_reduce<<<dim3(64,10), 256, 0, stream>>>(Ppart, P);
    k2_max   <<<dim3(125,4),  256, 0, stream>>>(L, W, P, maxbits);
    k3_out   <<<dim3(125,4),  256, 0, stream>>>(L, W, P, maxbits, out);
}

// Round 3
// 381.431 us; speedup vs baseline: 2.5780x; 1.0748x over previous
//
#include <hip/hip_runtime.h>
#include <math.h>

#define ALPHA_F 0.4f
#define FP32_EPS 1.1920928955078125e-7f
#define NB 256
#define NV 128000
#define NR 64

typedef _Float16 half_t;
typedef _Float16 half2_t __attribute__((ext_vector_type(2)));
typedef _Float16 half4_t __attribute__((ext_vector_type(4)));
typedef _Float16 half8 __attribute__((ext_vector_type(8)));
typedef float f32x4 __attribute__((ext_vector_type(4)));

// ---------------------------------------------------------------------------
// Scratch layouts.
// FAST (ws_size >= 140 MB; observed ~524 MB poison fill => expect FAST):
//   ws +0      : maxbits[2]
//   ws +256    : P[256*64] f32
//   ws +1  MiB : Ppart  (2000 x 64x64 f32, 32.77 MB)
//   ws +34 MiB : Wg     (k1 B-frags fp16, 16.4 MB)
//   ws +51 MiB : Wf     (k2/k3 B-frags fp16, 16.4 MB)
//   ws +68 MiB : Lh     (L as fp16, 65.5 MB)
// FALLBACK: maxbits/P in ws; Ppart @ d_out+0, Wg @ d_out+33MiB (dead before
//   k3); no Wf/Lh — k2/k3 read fp32 L and W directly.
// ---------------------------------------------------------------------------

// ---------- k0: build fp16 W fragments; zero P / maxbits ----------
__global__ __launch_bounds__(256) void k0_prep(const float* __restrict__ W,
                                               half_t* __restrict__ Wg,
                                               half_t* __restrict__ Wf,
                                               float* __restrict__ P,
                                               unsigned* __restrict__ maxbits) {
    __shared__ half_t tile[256 * 72];   // stride 72 halves = 144 B (16B-aligned rows)
    const int t  = threadIdx.x;
    const int k0 = blockIdx.x * 256;

    if (blockIdx.x < 64) P[blockIdx.x * 256 + t] = 0.f;
    if (blockIdx.x == 0 && t < 2) maxbits[t] = 0u;

    // coalesced read of W[256k x 64n] tile, cvt fp16 -> LDS
#pragma unroll
    for (int i = 0; i < 16; ++i) {
        const int f  = i * 256 + t;
        const int kr = f >> 4;
        const int n4 = (f & 15) * 4;
        const float4 v = *(const float4*)(W + (size_t)(k0 + kr) * NR + n4);
        half2_t h01 = { (half_t)v.x, (half_t)v.y };
        half2_t h23 = { (half_t)v.z, (half_t)v.w };
        *(half2_t*)&tile[kr * 72 + n4]     = h01;
        *(half2_t*)&tile[kr * 72 + n4 + 2] = h23;
    }
    __syncthreads();

    // Wg: B-frags for P = L@W (transposed gather). frag(kt,nt,lane=(q,il))[j]
    //   = W[kt*32 + q*8 + j][nt*16 + il]
#pragma unroll
    for (int i = 0; i < 8; ++i) {
        const int idx  = i * 256 + t;        // 0..2047
        const int kk_l = idx >> 8;           // 0..7
        const int rem  = idx & 255;
        const int nt   = rem >> 6;
        const int lane = rem & 63;
        const int q = lane >> 4, il = lane & 15;
        half8 v;
#pragma unroll
        for (int j = 0; j < 8; ++j)
            v[j] = tile[(kk_l * 32 + q * 8 + j) * 72 + nt * 16 + il];
        const int kt = blockIdx.x * 8 + kk_l;
        *(half8*)(Wg + ((size_t)(kt * 4 + nt) * 64 + lane) * 8) = v;
    }

    // Wf: B-frags for Lp = P@W^T (no transpose). frag(vt,ks,lane=(q,il))[j]
    //   = W[vt*16 + il][ks*32 + q*8 + j]   (contiguous ds_read_b128)
    if (Wf) {
#pragma unroll
        for (int i = 0; i < 8; ++i) {
            const int idx  = i * 256 + t;
            const int vt_l = idx >> 7;       // 0..15
            const int ks   = (idx >> 6) & 1;
            const int lane = idx & 63;
            const int q = lane >> 4, il = lane & 15;
            half8 v = *(const half8*)&tile[(vt_l * 16 + il) * 72 + ks * 32 + q * 8];
            const int vt = blockIdx.x * 16 + vt_l;
            *(half8*)(Wf + ((size_t)(vt * 2 + ks) * 64 + lane) * 8) = v;
        }
    }
}

// ---------- k1: split-K MFMA partials of P = L @ W; emit Lh; max|L| ----------
// grid (500 K-chunks of 256, 4 m-quarters); block 256 = 4 waves (16 rows each).
__global__ __launch_bounds__(256) void k1_pmm(const float* __restrict__ L,
                                              const half_t* __restrict__ Wg,
                                              float* __restrict__ Ppart,
                                              half_t* __restrict__ Lh,
                                              unsigned* __restrict__ maxbits) {
    const int l  = threadIdx.x & 63;
    const int w  = threadIdx.x >> 6;
    const int q  = l >> 4;
    const int il = l & 15;
    const int chunk = blockIdx.x;
    const int mq    = blockIdx.y;
    const int row   = mq * 64 + w * 16 + il;
    const size_t rowbase = (size_t)row * NV;

    f32x4 acc[4] = {};
    float amax = 0.f;

    for (int ks = 0; ks < 8; ++ks) {
        const int kk = chunk * 256 + ks * 32;
        const int kt = chunk * 8 + ks;
        half8 b[4];
#pragma unroll
        for (int nt = 0; nt < 4; ++nt)
            b[nt] = *(const half8*)(Wg + ((size_t)(kt * 4 + nt) * 64 + l) * 8);
        const float* lp = L + rowbase + kk + q * 8;
        const float4 f0 = *(const float4*)lp;
        const float4 f1 = *(const float4*)(lp + 4);
        amax = fmaxf(amax, fmaxf(fmaxf(fabsf(f0.x), fabsf(f0.y)),
                                 fmaxf(fabsf(f0.z), fabsf(f0.w))));
        amax = fmaxf(amax, fmaxf(fmaxf(fabsf(f1.x), fabsf(f1.y)),
                                 fmaxf(fabsf(f1.z), fabsf(f1.w))));
        half8 a = { (half_t)f0.x, (half_t)f0.y, (half_t)f0.z, (half_t)f0.w,
                    (half_t)f1.x, (half_t)f1.y, (half_t)f1.z, (half_t)f1.w };
        if (Lh) *(half8*)(Lh + rowbase + kk + q * 8) = a;
#pragma unroll
        for (int nt = 0; nt < 4; ++nt)
            acc[nt] = __builtin_amdgcn_mfma_f32_16x16x32_f16(a, b[nt], acc[nt], 0, 0, 0);
    }

    float* pb = Ppart + (size_t)(chunk * 4 + mq) * 4096;
#pragma unroll
    for (int nt = 0; nt < 4; ++nt)
#pragma unroll
        for (int i = 0; i < 4; ++i)
            pb[(w * 16 + q * 4 + i) * 64 + nt * 16 + il] = acc[nt][i];

#pragma unroll
    for (int off = 32; off > 0; off >>= 1)
        amax = fmaxf(amax, __shfl_xor(amax, off, 64));
    __shared__ float red[4];
    if (l == 0) red[w] = amax;
    __syncthreads();
    if (threadIdx.x == 0) {
        float m = fmaxf(fmaxf(red[0], red[1]), fmaxf(red[2], red[3]));
        atomicMax(&maxbits[0], __float_as_uint(m));
    }
}

// ---------- k1b: reduce Ppart -> P (atomicAdd partial sums) ----------
// grid (64, 5): y handles chunks [y*100, y*100+100)
__global__ __launch_bounds__(256) void k1b_reduce(const float* __restrict__ Ppart,
                                                  float* __restrict__ P) {
    const int g  = blockIdx.x * 256 + threadIdx.x;  // 0..16383
    const int M  = g >> 6, n = g & 63;
    const int mq = M >> 6, r = M & 63;
    const float* p = Ppart + ((size_t)(blockIdx.y * 100) * 4 + mq) * 4096 + r * 64 + n;
    float s = 0.f;
#pragma unroll 4
    for (int c = 0; c < 100; ++c) s += p[(size_t)c * 4 * 4096];
    atomicAdd(&P[g], s);
}

// ---------- k2/k3: T = P@W^T tile -> LDS; streaming epilogue ----------
// grid (1000 n-chunks of 128, 4 m-quarters); block 256; LDS T[64][132].
template <bool FAST, bool IS_OUT>
__global__ __launch_bounds__(256) void k23(const float* __restrict__ L,
                                           const half_t* __restrict__ Lh,
                                           const float* __restrict__ W,
                                           const half_t* __restrict__ Wf,
                                           const float* __restrict__ P,
                                           unsigned* __restrict__ maxbits,
                                           float* __restrict__ out) {
    __shared__ float T[64 * 132];
    __shared__ float red[4];
    const int l  = threadIdx.x & 63;
    const int w  = threadIdx.x >> 6;
    const int q  = l >> 4;
    const int il = l & 15;
    const int nc = blockIdx.x;
    const int mq = blockIdx.y;

    // phase A: MFMA 64 rows x 128 cols; wave w covers cols w*32..+32
    half8 a[4][2];
#pragma unroll
    for (int mt = 0; mt < 4; ++mt)
#pragma unroll
        for (int ks = 0; ks < 2; ++ks) {
            const float* pp = P + (size_t)(mq * 64 + mt * 16 + il) * NR + ks * 32 + q * 8;
            const float4 f0 = *(const float4*)pp;
            const float4 f1 = *(const float4*)(pp + 4);
            a[mt][ks] = { (half_t)f0.x, (half_t)f0.y, (half_t)f0.z, (half_t)f0.w,
                          (half_t)f1.x, (half_t)f1.y, (half_t)f1.z, (half_t)f1.w };
        }
#pragma unroll
    for (int ntl = 0; ntl < 2; ++ntl) {
        const int vt = nc * 8 + w * 2 + ntl;
        half8 b[2];
        if (FAST) {
#pragma unroll
            for (int ks = 0; ks < 2; ++ks)
                b[ks] = *(const half8*)(Wf + ((size_t)(vt * 2 + ks) * 64 + l) * 8);
        } else {
#pragma unroll
            for (int ks = 0; ks < 2; ++ks) {
                const float* wp = W + (size_t)(vt * 16 + il) * NR + ks * 32 + q * 8;
                const float4 f0 = *(const float4*)wp;
                const float4 f1 = *(const float4*)(wp + 4);
                b[ks] = { (half_t)f0.x, (half_t)f0.y, (half_t)f0.z, (half_t)f0.w,
                          (half_t)f1.x, (half_t)f1.y, (half_t)f1.z, (half_t)f1.w };
            }
        }
#pragma unroll
        for (int mt = 0; mt < 4; ++mt) {
            f32x4 acc = {};
            acc = __builtin_amdgcn_mfma_f32_16x16x32_f16(a[mt][0], b[0], acc, 0, 0, 0);
            acc = __builtin_amdgcn_mfma_f32_16x16x32_f16(a[mt][1], b[1], acc, 0, 0, 0);
#pragma unroll
            for (int i = 0; i < 4; ++i)
                T[(mt * 16 + q * 4 + i) * 132 + w * 32 + ntl * 16 + il] = acc[i];
        }
    }
    __syncthreads();

    // phase B: coalesced streaming over the 64x128 tile
    float c1 = 0.f, mx = 0.f;
    if (IS_OUT) {
        const float maxL  = __uint_as_float(maxbits[0]);
        const float maxLp = fmaxf(__uint_as_float(maxbits[1]), FP32_EPS);
        c1 = (1.f - ALPHA_F) * (maxL / maxLp);
    }
#pragma unroll
    for (int i = 0; i < 8; ++i) {
        const int e = i * 1024 + threadIdx.x * 4;
        const int r = e >> 7, c = e & 127;
        const size_t gaddr = (size_t)(mq * 64 + r) * NV + nc * 128 + c;
        const float4 tv = *(const float4*)&T[r * 132 + c];
        float4 lv;
        if (FAST) {
            const half4_t lh = *(const half4_t*)(Lh + gaddr);
            lv = make_float4((float)lh[0], (float)lh[1], (float)lh[2], (float)lh[3]);
        } else {
            lv = *(const float4*)(L + gaddr);
        }
        if (IS_OUT) {
            float4 o;
            o.x = fmaf(c1, tv.x - lv.x, ALPHA_F * lv.x);
            o.y = fmaf(c1, tv.y - lv.y, ALPHA_F * lv.y);
            o.z = fmaf(c1, tv.z - lv.z, ALPHA_F * lv.z);
            o.w = fmaf(c1, tv.w - lv.w, ALPHA_F * lv.w);
            *(float4*)(out + gaddr) = o;
        } else {
            mx = fmaxf(mx, fmaxf(fmaxf(fabsf(tv.x - lv.x), fabsf(tv.y - lv.y)),
                                 fmaxf(fabsf(tv.z - lv.z), fabsf(tv.w - lv.w))));
        }
    }
    if (!IS_OUT) {
#pragma unroll
        for (int off = 32; off > 0; off >>= 1)
            mx = fmaxf(mx, __shfl_xor(mx, off, 64));
        if (l == 0) red[w] = mx;
        __syncthreads();
        if (threadIdx.x == 0) {
            float m = fmaxf(fmaxf(red[0], red[1]), fmaxf(red[2], red[3]));
            atomicMax(&maxbits[1], __float_as_uint(m));
        }
    }
}

extern "C" void kernel_launch(void* const* d_in, const int* in_sizes, int n_in,
                              void* d_out, int out_size, void* d_ws, size_t ws_size,
                              hipStream_t stream) {
    const float* L = (const float*)d_in[1];   // logits [256,128000] fp32
    const float* W = (const float*)d_in[2];   // W [128000,64] fp32
    float* out = (float*)d_out;

    unsigned* maxbits = (unsigned*)d_ws;
    float*    P       = (float*)((char*)d_ws + 256);

    const bool fast = ws_size >= (size_t)140 * 1024 * 1024;
    float* Ppart; half_t* Wg; half_t* Wf; half_t* Lh;
    char* ws = (char*)d_ws;
    if (fast) {
        Ppart = (float*)(ws + ((size_t)1  << 20));
        Wg    = (half_t*)(ws + ((size_t)34 << 20));
        Wf    = (half_t*)(ws + ((size_t)51 << 20));
        Lh    = (half_t*)(ws + ((size_t)68 << 20));
    } else {
        Ppart = (float*)d_out;                             // dead before k3
        Wg    = (half_t*)((char*)d_out + ((size_t)33 << 20));
        Wf    = nullptr;
        Lh    = nullptr;
    }

    k0_prep   <<<500,           256, 0, stream>>>(W, Wg, Wf, P, maxbits);
    k1_pmm    <<<dim3(500, 4),  256, 0, stream>>>(L, Wg, Ppart, Lh, maxbits);
    k1b_reduce<<<dim3(64, 5),   256, 0, stream>>>(Ppart, P);
    if (fast) {
        k23<true,  false><<<dim3(1000, 4), 256, 0, stream>>>(L, Lh, W, Wf, P, maxbits, out);
        k23<true,  true ><<<dim3(1000, 4), 256, 0, stream>>>(L, Lh, W, Wf, P, maxbits, out);
    } else {
        k23<false, false><<<dim3(1000, 4), 256, 0, stream>>>(L, Lh, W, Wf, P, maxbits, out);
        k23<false, true ><<<dim3(1000, 4), 256, 0, stream>>>(L, Lh, W, Wf, P, maxbits, out);
    }
}